// Round 5
// baseline (294.180 us; speedup 1.0000x reference)
//
#include <hip/hip_runtime.h>
#include <hip/hip_bf16.h>
#include <stdint.h>

using bf16   = __hip_bfloat16;
using short8 = __attribute__((ext_vector_type(8))) short;
using f32x4  = __attribute__((ext_vector_type(4))) float;
using f32x16 = __attribute__((ext_vector_type(16))) float;

#define NSEQ   2048
#define NHEADS 16
#define DK     64
#define DMODEL 1024

#define GLDS16(gp, lp) __builtin_amdgcn_global_load_lds( \
    (const __attribute__((address_space(1))) void*)(gp), \
    (__attribute__((address_space(3))) void*)(lp), 16, 0, 0)

__device__ __forceinline__ ushort f2bf(float f){
  bf16 h = __float2bfloat16(f);
  return __builtin_bit_cast(ushort, h);
}
__device__ __forceinline__ float bf2f(ushort u){
  uint t = ((uint)u)<<16; return __builtin_bit_cast(float, t);
}

// ---------------- fp32 -> bf16 convert ----------------
__global__ void k_cvt(const float4* __restrict__ src, ushort4* __restrict__ dst, int n4){
  int i = blockIdx.x*blockDim.x + threadIdx.x;
  if (i >= n4) return;
  float4 v = src[i];
  ushort4 o;
  o.x = f2bf(v.x); o.y = f2bf(v.y); o.z = f2bf(v.z); o.w = f2bf(v.w);
  dst[i] = o;
}

// ---------------- geometry feature tables (bf16 hi/lo split) ----------------
// d^2(q,k) = dot(AF[k], BF[q]) over 16 slots.
__global__ void k_geo(const float* __restrict__ pos, ushort* __restrict__ AF,
                      ushort* __restrict__ BF, int n){
  int i = blockIdx.x*blockDim.x + threadIdx.x;
  if (i >= n) return;
  float x = pos[i*3+0], y = pos[i*3+1], z = pos[i*3+2];
  float sq = x*x + y*y + z*z;
  ushort xh = f2bf(x);  float xhf = bf2f(xh);  ushort xl = f2bf(x - xhf);
  ushort yh = f2bf(y);  float yhf = bf2f(yh);  ushort yl = f2bf(y - yhf);
  ushort zh = f2bf(z);  float zhf = bf2f(zh);  ushort zl = f2bf(z - zhf);
  ushort sh = f2bf(sq); float shf = bf2f(sh);  ushort sl = f2bf(sq - shf);
  ushort m2xh = f2bf(-2.f*xhf), m2xl = f2bf(-2.f*bf2f(xl));
  ushort m2yh = f2bf(-2.f*yhf), m2yl = f2bf(-2.f*bf2f(yl));
  ushort m2zh = f2bf(-2.f*zhf), m2zl = f2bf(-2.f*bf2f(zl));
  const ushort one = 0x3F80;
  ushort af[16] = {xh,xl,xh, yh,yl,yh, zh,zl,zh, sh,sl, one,one, 0,0,0};
  ushort bv[16] = {m2xh,m2xh,m2xl, m2yh,m2yh,m2yl, m2zh,m2zh,m2zl, one,one, sh,sl, 0,0,0};
  *(uint4*)&AF[i*16]     = *(uint4*)&af[0];
  *(uint4*)&AF[i*16 + 8] = *(uint4*)&af[8];
  *(uint4*)&BF[i*16]     = *(uint4*)&bv[0];
  *(uint4*)&BF[i*16 + 8] = *(uint4*)&bv[8];
}

// ---- 128x128 (K=1024) bf16 MFMA GEMM core: C[m,n] = sum_k A[m,k]*B[n,k] ----
__device__ __forceinline__ void gemm_core(
    const ushort* __restrict__ Ap, const ushort* __restrict__ Bp,
    int bm, int bn, int tid, ushort smem[2][2][4096], f32x4 (&acc)[4][4])
{
  const int wave = tid>>6, lane = tid&63;
  const int wr = wave>>1, wc = wave&1;
  const int ko   = (lane>>4)*8;
  const int srow = wave*16 + (lane>>2);
  const int scol = (lane&3)*8;

  const ushort* As = Ap + (size_t)(bm*128)*DMODEL + scol;
  const ushort* Bs = Bp + (size_t)(bn*128)*DMODEL + scol;

#define STAGE(buf, kt) do { \
    _Pragma("unroll") \
    for (int i_=0;i_<2;i_++){ \
      GLDS16(As + (size_t)(i_*64 + srow)*DMODEL + (kt)*32, &smem[buf][0][i_*2048 + wave*512]); \
      GLDS16(Bs + (size_t)(i_*64 + srow)*DMODEL + (kt)*32, &smem[buf][1][i_*2048 + wave*512]); \
    } } while(0)

  STAGE(0, 0);
  for (int kt=0; kt<32; ++kt){
    int cur = kt&1;
    __syncthreads();
    if (kt<31) STAGE(cur^1, kt+1);
    short8 af[4], bfv[4];
    const ushort* At = smem[cur][0];
    const ushort* Bt = smem[cur][1];
    #pragma unroll
    for (int mi=0;mi<4;mi++) af[mi]  = *(const short8*)&At[(wr*64+mi*16+(lane&15))*32 + ko];
    #pragma unroll
    for (int ni=0;ni<4;ni++) bfv[ni] = *(const short8*)&Bt[(wc*64+ni*16+(lane&15))*32 + ko];
    #pragma unroll
    for (int mi=0;mi<4;mi++)
      #pragma unroll
      for (int ni=0;ni<4;ni++)
        acc[mi][ni] = __builtin_amdgcn_mfma_f32_16x16x32_bf16(af[mi], bfv[ni], acc[mi][ni], 0,0,0);
  }
#undef STAGE
}

// ---------------- fused QKV projection ----------------
__global__ __launch_bounds__(256) void k_gemm_qkv(
    const ushort* __restrict__ xb,
    const ushort* __restrict__ Wqb, const ushort* __restrict__ Wkb, const ushort* __restrict__ Wvb,
    const float* __restrict__ bq, const float* __restrict__ bk, const float* __restrict__ bv,
    ushort* __restrict__ Qo, ushort* __restrict__ Ko, ushort* __restrict__ Vto)
{
  __shared__ ushort smem[2][2][4096];
  const int tid = threadIdx.x;
  const int t = blockIdx.x & 255;
  const int z = blockIdx.x >> 8;
  const int lane = tid&63, wave = tid>>6;
  const int wr = wave>>1, wc = wave&1;

  const ushort* Ap; const ushort* Bp; const float* bias;
  ushort* outp; int bm, bn; float scale = 1.0f;
  if (z==0){ Ap=xb;  Bp=Wqb; bias=bq; outp=Qo;  bm=t>>3; bn=t&7; scale=0.125f; }
  else if (z==1){ Ap=xb;  Bp=Wkb; bias=bk; outp=Ko;  bm=t>>3; bn=t&7; }
  else          { Ap=Wvb; Bp=xb;  bias=bv; outp=Vto; bm=t&7;  bn=t>>3; }

  f32x4 acc[4][4] = {};
  gemm_core(Ap, Bp, bm, bn, tid, smem, acc);

  if (z<2){
    #pragma unroll
    for (int mi=0;mi<4;mi++){
      const int m0 = bm*128 + wr*64 + mi*16 + (lane>>4)*4;
      #pragma unroll
      for (int ni=0;ni<4;ni++){
        const int nn = bn*128 + wc*64 + ni*16 + (lane&15);
        const float bs = bias[nn];
        const int h = nn>>6, d = nn&63;
        #pragma unroll
        for (int j=0;j<4;j++){
          int mm = m0+j;
          int b = mm>>11, nr = mm&2047;
          size_t off = (((size_t)(b*NHEADS+h)*NSEQ) + nr)*DK + d;
          outp[off] = f2bf((acc[mi][ni][j] + bs)*scale);
        }
      }
    }
  } else {
    #pragma unroll
    for (int mi=0;mi<4;mi++){
      const int m0 = bm*128 + wr*64 + mi*16 + (lane>>4)*4;
      #pragma unroll
      for (int ni=0;ni<4;ni++){
        const int nn = bn*128 + wc*64 + ni*16 + (lane&15);
        const int b = nn>>11, nr = nn&2047;
        #pragma unroll
        for (int j=0;j<4;j++){
          int mm = m0+j;
          const float bs = bias[mm];
          int h = mm>>6, d = mm&63;
          size_t off = (((size_t)(b*NHEADS+h)*DK) + d)*NSEQ + nr;
          outp[off] = f2bf(acc[mi][ni][j] + bs);
        }
      }
    }
  }
}

// ---------------- output projection ----------------
__global__ __launch_bounds__(256) void k_gemm_out(
    const ushort* __restrict__ Ob, const ushort* __restrict__ Wob,
    const float* __restrict__ bo, float* __restrict__ out)
{
  __shared__ ushort smem[2][2][4096];
  const int tid = threadIdx.x;
  const int t = blockIdx.x;
  const int lane = tid&63, wave = tid>>6;
  const int wr = wave>>1, wc = wave&1;
  const int bm = t>>3, bn = t&7;
  f32x4 acc[4][4] = {};
  gemm_core(Ob, Wob, bm, bn, tid, smem, acc);
  #pragma unroll
  for (int mi=0;mi<4;mi++){
    const int m0 = bm*128 + wr*64 + mi*16 + (lane>>4)*4;
    #pragma unroll
    for (int ni=0;ni<4;ni++){
      const int nn = bn*128 + wc*64 + ni*16 + (lane&15);
      const float bs = bo[nn];
      #pragma unroll
      for (int j=0;j<4;j++)
        out[(size_t)(m0+j)*DMODEL + nn] = acc[mi][ni][j] + bs;
    }
  }
}

// ---------------- flash attention: swapped-QK 32x32, d^2 via MFMA, no max ----------------
// grid (64 qtiles, 16 heads, 2 batch); 4 waves/block; all waves share one 32-q
// tile, wave w covers k-rows [w*512, (w+1)*512). Cross-wave merge in LDS (fp32),
// wave 0 normalizes and writes O. No global partials, no separate merge kernel.
__global__ __launch_bounds__(256) void k_attn(
    const ushort* __restrict__ Q, const ushort* __restrict__ K, const ushort* __restrict__ Vt,
    const ushort* __restrict__ AF, const ushort* __restrict__ BF,
    const float* __restrict__ dist_bias,
    ushort* __restrict__ O)
{
  __shared__ float red[2][2048];    // 2 x 8KB swizzled fp32 merge buffers
  __shared__ float lred[4][32];
  const int tid = threadIdx.x, wave = tid>>6, lane = tid&63;
  const int qt = blockIdx.x, h = blockIdx.y, b = blockIdx.z;
  const int lo5 = lane&31, hi = lane>>5;
  const float ah = fabsf(dist_bias[h]);
  const ushort* Qh  = Q  + ((size_t)(b*NHEADS+h))*NSEQ*DK;
  const ushort* Kh  = K  + ((size_t)(b*NHEADS+h))*NSEQ*DK;
  const ushort* Vth = Vt + ((size_t)(b*NHEADS+h))*DK*NSEQ;
  const ushort* AFb = AF + (size_t)b*NSEQ*16;
  const ushort* BFb = BF + (size_t)b*NSEQ*16;

  const int q0 = qt*32;

  short8 qf[4];
  #pragma unroll
  for (int s=0;s<4;s++)
    qf[s] = *(const short8*)&Qh[(size_t)(q0+lo5)*DK + s*16 + hi*8];
  const short8 bfq = *(const short8*)&BFb[(size_t)(q0+lo5)*16 + hi*8];

  f32x16 o0 = {}, o1 = {};
  float l_run = 0.f;
  const int j0 = wave*512;

  for (int jt=0; jt<16; ++jt){
    const int jb = j0 + jt*32;
    // ---- d^2 tile via MFMA ----
    const short8 afk = *(const short8*)&AFb[(size_t)(jb+lo5)*16 + hi*8];
    f32x16 zz = {};
    f32x16 d2 = __builtin_amdgcn_mfma_f32_32x32x16_bf16(afk, bfq, zz, 0,0,0);
    // ---- S^T = K Q^T (Q pre-scaled by 1/8) ----
    f32x16 st = {};
    #pragma unroll
    for (int s=0;s<4;s++){
      short8 kf = *(const short8*)&Kh[(size_t)(jb+lo5)*DK + s*16 + hi*8];
      st = __builtin_amdgcn_mfma_f32_32x32x16_bf16(kf, qf[s], st, 0,0,0);
    }
    // ---- V loads issued early (independent of softmax) ----
    const short8 v00 = *(const short8*)&Vth[(size_t)(lo5)*NSEQ      + jb      + hi*8];
    const short8 v01 = *(const short8*)&Vth[(size_t)(lo5)*NSEQ      + jb + 16 + hi*8];
    const short8 v10 = *(const short8*)&Vth[(size_t)(32+lo5)*NSEQ   + jb      + hi*8];
    const short8 v11 = *(const short8*)&Vth[(size_t)(32+lo5)*NSEQ   + jb + 16 + hi*8];
    // ---- p = exp(st - a*d), no max needed (logit range analysis) ----
    float p[16];
    #pragma unroll
    for (int r=0;r<16;r++){
      float d = __builtin_amdgcn_sqrtf(fmaxf(d2[r], 0.f));
      p[r] = __expf(fmaf(-ah, d, st[r]));
    }
    float s01=p[0]+p[1], s23=p[2]+p[3], s45=p[4]+p[5], s67=p[6]+p[7];
    float s89=p[8]+p[9], sab=p[10]+p[11], scd=p[12]+p[13], sef=p[14]+p[15];
    float rsum = ((s01+s23)+(s45+s67)) + ((s89+sab)+(scd+sef));
    rsum += __shfl_xor(rsum, 32);
    l_run += rsum;
    // ---- P -> bf16 A-fragments (cvt_pk + permlane32_swap), PV ----
    #pragma unroll
    for (int s=0;s<2;s++){
      uint w0, w1, w2, w3;
      asm("v_cvt_pk_bf16_f32 %0, %1, %2" : "=v"(w0) : "v"(p[8*s+0]), "v"(p[8*s+1]));
      asm("v_cvt_pk_bf16_f32 %0, %1, %2" : "=v"(w2) : "v"(p[8*s+4]), "v"(p[8*s+5]));
      asm("v_cvt_pk_bf16_f32 %0, %1, %2" : "=v"(w1) : "v"(p[8*s+2]), "v"(p[8*s+3]));
      asm("v_cvt_pk_bf16_f32 %0, %1, %2" : "=v"(w3) : "v"(p[8*s+6]), "v"(p[8*s+7]));
      asm volatile("v_permlane32_swap_b32 %0, %1" : "+v"(w0), "+v"(w2));
      asm volatile("v_permlane32_swap_b32 %0, %1" : "+v"(w1), "+v"(w3));
      uint4 aw; aw.x = w0; aw.y = w1; aw.z = w2; aw.w = w3;
      const short8 pa = __builtin_bit_cast(short8, aw);
      if (s==0){
        o0 = __builtin_amdgcn_mfma_f32_32x32x16_bf16(pa, v00, o0, 0,0,0);
        o1 = __builtin_amdgcn_mfma_f32_32x32x16_bf16(pa, v10, o1, 0,0,0);
      } else {
        o0 = __builtin_amdgcn_mfma_f32_32x32x16_bf16(pa, v01, o0, 0,0,0);
        o1 = __builtin_amdgcn_mfma_f32_32x32x16_bf16(pa, v11, o1, 0,0,0);
      }
    }
  }

  // ---- cross-wave fp32 merge in LDS (tree: 2,3 -> 0,1; 1 -> 0) ----
  // slot rotation (g+lane)&7 keeps b128 accesses bank-uniform.
#define STORE_ACC(buf) do { \
    float* rb = red[buf]; \
    _Pragma("unroll") \
    for (int g=0; g<8; ++g){ \
      const int sl = (g + lane) & 7; \
      float4 t; \
      if (g<4){ t.x=o0[g*4]; t.y=o0[g*4+1]; t.z=o0[g*4+2]; t.w=o0[g*4+3]; } \
      else    { t.x=o1[(g-4)*4]; t.y=o1[(g-4)*4+1]; t.z=o1[(g-4)*4+2]; t.w=o1[(g-4)*4+3]; } \
      *(float4*)&rb[lane*32 + sl*4] = t; \
    } } while(0)
#define LOAD_ADD_ACC(buf) do { \
    const float* rb = red[buf]; \
    _Pragma("unroll") \
    for (int g=0; g<8; ++g){ \
      const int sl = (g + lane) & 7; \
      float4 t = *(const float4*)&rb[lane*32 + sl*4]; \
      if (g<4){ o0[g*4]+=t.x; o0[g*4+1]+=t.y; o0[g*4+2]+=t.z; o0[g*4+3]+=t.w; } \
      else    { o1[(g-4)*4]+=t.x; o1[(g-4)*4+1]+=t.y; o1[(g-4)*4+2]+=t.z; o1[(g-4)*4+3]+=t.w; } \
    } } while(0)

  if (wave >= 2) STORE_ACC(wave-2);
  if (wave != 0 && hi == 0) lred[wave][lo5] = l_run;
  __syncthreads();
  if (wave < 2) LOAD_ADD_ACC(wave);
  __syncthreads();
  if (wave == 1) STORE_ACC(0);
  __syncthreads();
  if (wave == 0){
    LOAD_ADD_ACC(0);
    l_run += lred[1][lo5] + lred[2][lo5] + lred[3][lo5];
    #pragma unroll
    for (int r=0;r<16;r++){
      const int src = (r&3) + 8*(r>>2) + 4*hi;
      const float lr = __shfl(l_run, src);
      const float inv = 1.f/lr;
      const int i = q0 + src;
      O[((size_t)b*NSEQ + i)*DMODEL + h*DK + lo5]      = f2bf(o0[r]*inv);
      O[((size_t)b*NSEQ + i)*DMODEL + h*DK + 32 + lo5] = f2bf(o1[r]*inv);
    }
  }
#undef STORE_ACC
#undef LOAD_ADD_ACC
}

extern "C" void kernel_launch(void* const* d_in, const int* in_sizes, int n_in,
                              void* d_out, int out_size, void* d_ws, size_t ws_size,
                              hipStream_t stream) {
  const float* x   = (const float*)d_in[0];
  const float* pos = (const float*)d_in[1];
  const float* Wq  = (const float*)d_in[2];
  const float* bq  = (const float*)d_in[3];
  const float* Wk  = (const float*)d_in[4];
  const float* bk  = (const float*)d_in[5];
  const float* Wv  = (const float*)d_in[6];
  const float* bv  = (const float*)d_in[7];
  const float* Wo  = (const float*)d_in[8];
  const float* bo  = (const float*)d_in[9];
  const float* db  = (const float*)d_in[10];
  float* out = (float*)d_out;

  // workspace layout (48 MB, regions reused across phases):
  // 0-8MB   : xb (x bf16)            -> merged O (after attn)
  // 8-10MB  : Wqb                    -> AF(128K) + BF(128K)
  // 10-12MB : Wkb   (dead after qkv gemm)
  // 12-14MB : Wvb   (dead after qkv gemm)
  // 14-16MB : Wob   (live until k_gemm_out)
  // 16-24MB : Qb
  // 24-32MB : Kb
  // 32-40MB : Vtb
  char* ws = (char*)d_ws;
  ushort* xb   = (ushort*)(ws);
  ushort* Wqb  = (ushort*)(ws + ((size_t)8<<20));
  ushort* Wkb  = (ushort*)(ws + ((size_t)10<<20));
  ushort* Wvb  = (ushort*)(ws + ((size_t)12<<20));
  ushort* Wob  = (ushort*)(ws + ((size_t)14<<20));
  ushort* Qb   = (ushort*)(ws + ((size_t)16<<20));
  ushort* Kb   = (ushort*)(ws + ((size_t)24<<20));
  ushort* Vtb  = (ushort*)(ws + ((size_t)32<<20));
  ushort* AFt  = Wqb;                                  // reuse after qkv gemm
  ushort* BFt  = (ushort*)(ws + ((size_t)8<<20) + (128<<10));
  ushort* Omrg = xb;                                   // reuse after qkv gemm

  k_cvt<<<4096, 256, 0, stream>>>((const float4*)x,  (ushort4*)xb,  1048576);
  k_cvt<<<1024, 256, 0, stream>>>((const float4*)Wq, (ushort4*)Wqb, 262144);
  k_cvt<<<1024, 256, 0, stream>>>((const float4*)Wk, (ushort4*)Wkb, 262144);
  k_cvt<<<1024, 256, 0, stream>>>((const float4*)Wv, (ushort4*)Wvb, 262144);
  k_cvt<<<1024, 256, 0, stream>>>((const float4*)Wo, (ushort4*)Wob, 262144);
  k_gemm_qkv<<<768, 256, 0, stream>>>(xb, Wqb, Wkb, Wvb, bq, bk, bv, Qb, Kb, Vtb);
  k_geo<<<16, 256, 0, stream>>>(pos, AFt, BFt, 2*NSEQ);
  k_attn<<<dim3(64,NHEADS,2), 256, 0, stream>>>(Qb, Kb, Vtb, AFt, BFt, db, Omrg);
  k_gemm_out<<<256, 256, 0, stream>>>(Omrg, Wob, bo, out);
}

// Round 6
// 237.058 us; speedup vs baseline: 1.2410x; 1.2410x over previous
//
#include <hip/hip_runtime.h>
#include <hip/hip_bf16.h>
#include <stdint.h>

using bf16   = __hip_bfloat16;
using short8 = __attribute__((ext_vector_type(8))) short;
using f32x4  = __attribute__((ext_vector_type(4))) float;
using f32x16 = __attribute__((ext_vector_type(16))) float;

#define NSEQ   2048
#define NHEADS 16
#define DK     64
#define DMODEL 1024

#define GLDS16(gp, lp) __builtin_amdgcn_global_load_lds( \
    (const __attribute__((address_space(1))) void*)(gp), \
    (__attribute__((address_space(3))) void*)(lp), 16, 0, 0)

__device__ __forceinline__ ushort f2bf(float f){
  bf16 h = __float2bfloat16(f);
  return __builtin_bit_cast(ushort, h);
}
__device__ __forceinline__ float bf2f(ushort u){
  uint t = ((uint)u)<<16; return __builtin_bit_cast(float, t);
}

// ---------------- fp32 -> bf16 convert ----------------
__global__ void k_cvt(const float4* __restrict__ src, ushort4* __restrict__ dst, int n4){
  int i = blockIdx.x*blockDim.x + threadIdx.x;
  if (i >= n4) return;
  float4 v = src[i];
  ushort4 o;
  o.x = f2bf(v.x); o.y = f2bf(v.y); o.z = f2bf(v.z); o.w = f2bf(v.w);
  dst[i] = o;
}

// ---------------- geometry feature tables (bf16 hi/lo split) ----------------
// d^2(q,k) = dot(AF[k], BF[q]) over 16 slots.
__global__ void k_geo(const float* __restrict__ pos, ushort* __restrict__ AF,
                      ushort* __restrict__ BF, int n){
  int i = blockIdx.x*blockDim.x + threadIdx.x;
  if (i >= n) return;
  float x = pos[i*3+0], y = pos[i*3+1], z = pos[i*3+2];
  float sq = x*x + y*y + z*z;
  ushort xh = f2bf(x);  float xhf = bf2f(xh);  ushort xl = f2bf(x - xhf);
  ushort yh = f2bf(y);  float yhf = bf2f(yh);  ushort yl = f2bf(y - yhf);
  ushort zh = f2bf(z);  float zhf = bf2f(zh);  ushort zl = f2bf(z - zhf);
  ushort sh = f2bf(sq); float shf = bf2f(sh);  ushort sl = f2bf(sq - shf);
  ushort m2xh = f2bf(-2.f*xhf), m2xl = f2bf(-2.f*bf2f(xl));
  ushort m2yh = f2bf(-2.f*yhf), m2yl = f2bf(-2.f*bf2f(yl));
  ushort m2zh = f2bf(-2.f*zhf), m2zl = f2bf(-2.f*bf2f(zl));
  const ushort one = 0x3F80;
  ushort af[16] = {xh,xl,xh, yh,yl,yh, zh,zl,zh, sh,sl, one,one, 0,0,0};
  ushort bv[16] = {m2xh,m2xh,m2xl, m2yh,m2yh,m2yl, m2zh,m2zh,m2zl, one,one, sh,sl, 0,0,0};
  *(uint4*)&AF[i*16]     = *(uint4*)&af[0];
  *(uint4*)&AF[i*16 + 8] = *(uint4*)&af[8];
  *(uint4*)&BF[i*16]     = *(uint4*)&bv[0];
  *(uint4*)&BF[i*16 + 8] = *(uint4*)&bv[8];
}

// ---- 128x128 (K=1024) bf16 MFMA GEMM core: C[m,n] = sum_k A[m,k]*B[n,k] ----
__device__ __forceinline__ void gemm_core(
    const ushort* __restrict__ Ap, const ushort* __restrict__ Bp,
    int bm, int bn, int tid, ushort smem[2][2][4096], f32x4 (&acc)[4][4])
{
  const int wave = tid>>6, lane = tid&63;
  const int wr = wave>>1, wc = wave&1;
  const int ko   = (lane>>4)*8;
  const int srow = wave*16 + (lane>>2);
  const int scol = (lane&3)*8;

  const ushort* As = Ap + (size_t)(bm*128)*DMODEL + scol;
  const ushort* Bs = Bp + (size_t)(bn*128)*DMODEL + scol;

#define STAGEG(buf, kt) do { \
    _Pragma("unroll") \
    for (int i_=0;i_<2;i_++){ \
      GLDS16(As + (size_t)(i_*64 + srow)*DMODEL + (kt)*32, &smem[buf][0][i_*2048 + wave*512]); \
      GLDS16(Bs + (size_t)(i_*64 + srow)*DMODEL + (kt)*32, &smem[buf][1][i_*2048 + wave*512]); \
    } } while(0)

  STAGEG(0, 0);
  for (int kt=0; kt<32; ++kt){
    int cur = kt&1;
    __syncthreads();
    if (kt<31) STAGEG(cur^1, kt+1);
    short8 af[4], bfv[4];
    const ushort* At = smem[cur][0];
    const ushort* Bt = smem[cur][1];
    #pragma unroll
    for (int mi=0;mi<4;mi++) af[mi]  = *(const short8*)&At[(wr*64+mi*16+(lane&15))*32 + ko];
    #pragma unroll
    for (int ni=0;ni<4;ni++) bfv[ni] = *(const short8*)&Bt[(wc*64+ni*16+(lane&15))*32 + ko];
    #pragma unroll
    for (int mi=0;mi<4;mi++)
      #pragma unroll
      for (int ni=0;ni<4;ni++)
        acc[mi][ni] = __builtin_amdgcn_mfma_f32_16x16x32_bf16(af[mi], bfv[ni], acc[mi][ni], 0,0,0);
  }
#undef STAGEG
}

// ---------------- fused QKV projection ----------------
__global__ __launch_bounds__(256) void k_gemm_qkv(
    const ushort* __restrict__ xb,
    const ushort* __restrict__ Wqb, const ushort* __restrict__ Wkb, const ushort* __restrict__ Wvb,
    const float* __restrict__ bq, const float* __restrict__ bk, const float* __restrict__ bv,
    ushort* __restrict__ Qo, ushort* __restrict__ Ko, ushort* __restrict__ Vto)
{
  __shared__ ushort smem[2][2][4096];
  const int tid = threadIdx.x;
  const int t = blockIdx.x & 255;
  const int z = blockIdx.x >> 8;
  const int lane = tid&63, wave = tid>>6;
  const int wr = wave>>1, wc = wave&1;

  const ushort* Ap; const ushort* Bp; const float* bias;
  ushort* outp; int bm, bn; float scale = 1.0f;
  if (z==0){ Ap=xb;  Bp=Wqb; bias=bq; outp=Qo;  bm=t>>3; bn=t&7; scale=0.125f; }
  else if (z==1){ Ap=xb;  Bp=Wkb; bias=bk; outp=Ko;  bm=t>>3; bn=t&7; }
  else          { Ap=Wvb; Bp=xb;  bias=bv; outp=Vto; bm=t&7;  bn=t>>3; }

  f32x4 acc[4][4] = {};
  gemm_core(Ap, Bp, bm, bn, tid, smem, acc);

  if (z<2){
    #pragma unroll
    for (int mi=0;mi<4;mi++){
      const int m0 = bm*128 + wr*64 + mi*16 + (lane>>4)*4;
      #pragma unroll
      for (int ni=0;ni<4;ni++){
        const int nn = bn*128 + wc*64 + ni*16 + (lane&15);
        const float bs = bias[nn];
        const int h = nn>>6, d = nn&63;
        #pragma unroll
        for (int j=0;j<4;j++){
          int mm = m0+j;
          int b = mm>>11, nr = mm&2047;
          size_t off = (((size_t)(b*NHEADS+h)*NSEQ) + nr)*DK + d;
          outp[off] = f2bf((acc[mi][ni][j] + bs)*scale);
        }
      }
    }
  } else {
    #pragma unroll
    for (int mi=0;mi<4;mi++){
      const int m0 = bm*128 + wr*64 + mi*16 + (lane>>4)*4;
      #pragma unroll
      for (int ni=0;ni<4;ni++){
        const int nn = bn*128 + wc*64 + ni*16 + (lane&15);
        const int b = nn>>11, nr = nn&2047;
        #pragma unroll
        for (int j=0;j<4;j++){
          int mm = m0+j;
          const float bs = bias[mm];
          int h = mm>>6, d = mm&63;
          size_t off = (((size_t)(b*NHEADS+h)*DK) + d)*NSEQ + nr;
          outp[off] = f2bf(acc[mi][ni][j] + bs);
        }
      }
    }
  }
}

// ---------------- output projection ----------------
__global__ __launch_bounds__(256) void k_gemm_out(
    const ushort* __restrict__ Ob, const ushort* __restrict__ Wob,
    const float* __restrict__ bo, float* __restrict__ out)
{
  __shared__ ushort smem[2][2][4096];
  const int tid = threadIdx.x;
  const int t = blockIdx.x;
  const int lane = tid&63, wave = tid>>6;
  const int wr = wave>>1, wc = wave&1;
  const int bm = t>>3, bn = t&7;
  f32x4 acc[4][4] = {};
  gemm_core(Ob, Wob, bm, bn, tid, smem, acc);
  #pragma unroll
  for (int mi=0;mi<4;mi++){
    const int m0 = bm*128 + wr*64 + mi*16 + (lane>>4)*4;
    #pragma unroll
    for (int ni=0;ni<4;ni++){
      const int nn = bn*128 + wc*64 + ni*16 + (lane&15);
      const float bs = bo[nn];
      #pragma unroll
      for (int j=0;j<4;j++)
        out[(size_t)(m0+j)*DMODEL + nn] = acc[mi][ni][j] + bs;
    }
  }
}

// ---------------- flash attention: LDS-staged K/V shared by 4 waves ----------------
// grid (16 qtiles, 16 heads, 2 batch); 4 waves/block; wave w owns q-rows
// [qt*128 + w*32, +32); ALL waves iterate over all 2048 k in 64-row tiles
// staged (double-buffered) in LDS via global_load_lds. Swizzled staging:
// LDS slot (row, c16) holds global (row, c16 ^ (row&7)); reads XOR back
// -> 4-way bank conflict instead of 32-way. No cross-wave merge needed.
__global__ __launch_bounds__(256) void k_attn(
    const ushort* __restrict__ Q, const ushort* __restrict__ K, const ushort* __restrict__ Vt,
    const ushort* __restrict__ AF, const ushort* __restrict__ BF,
    const float* __restrict__ dist_bias,
    ushort* __restrict__ O)
{
  __shared__ ushort kb[2][4096];   // K tile  [64 k-rows][64 dk]  (8KB each)
  __shared__ ushort vb[2][4096];   // Vt tile [64 d-rows][64 k]   (8KB each)
  const int tid = threadIdx.x, wave = tid>>6, lane = tid&63;
  const int qt = blockIdx.x, h = blockIdx.y, b = blockIdx.z;
  const int lo5 = lane&31, hi = lane>>5;
  const float ah = fabsf(dist_bias[h]);
  const ushort* Qh  = Q  + ((size_t)(b*NHEADS+h))*NSEQ*DK;
  const ushort* Kh  = K  + ((size_t)(b*NHEADS+h))*NSEQ*DK;
  const ushort* Vth = Vt + ((size_t)(b*NHEADS+h))*DK*NSEQ;
  const ushort* AFb = AF + (size_t)b*NSEQ*16;
  const ushort* BFb = BF + (size_t)b*NSEQ*16;

  const int q0 = qt*128 + wave*32;

  // Q B-fragments (persist): col=q0+lo5, k = s*16 + hi*8 + e
  short8 qf[4];
  #pragma unroll
  for (int s=0;s<4;s++)
    qf[s] = *(const short8*)&Qh[(size_t)(q0+lo5)*DK + s*16 + hi*8];
  const short8 bfq = *(const short8*)&BFb[(size_t)(q0+lo5)*16 + hi*8];

  // staging coords: slot s = p*256 + wave*64 + lane; row = s>>3, c16 = lane&7
  // row&7 == lane>>3, so swizzled global col16 = (lane&7) ^ (lane>>3).
  const int grow  = lane>>3;                 // 0..7
  const int gc16  = (lane&7) ^ grow;         // pre-swizzled source col16
  const int rowb  = wave*8 + grow;           // 0..31 (pass p adds p*32)

#define STAGE(buf, jb) do { \
    _Pragma("unroll") \
    for (int p_=0;p_<2;p_++){ \
      const int rw_ = p_*32 + rowb; \
      GLDS16(Kh  + (size_t)((jb)+rw_)*DK   + gc16*8, &kb[buf][(p_*256 + wave*64)*8]); \
      GLDS16(Vth + (size_t)rw_*NSEQ + (jb) + gc16*8, &vb[buf][(p_*256 + wave*64)*8]); \
    } } while(0)

  // read-side: row base (ushorts) and XOR key
  const int rb = lo5*64;
  const int rx = lo5 & 7;

  f32x16 o0 = {}, o1 = {};
  float l_run = 0.f;

  STAGE(0, 0);
  for (int t=0; t<32; ++t){
    const int cur = t&1;
    __syncthreads();                       // drains vmcnt -> tile cur ready
    if (t<31) STAGE(cur^1, (t+1)*64);
    const ushort* kbc = kb[cur];
    const ushort* vbc = vb[cur];
    #pragma unroll
    for (int ss=0; ss<2; ++ss){
      const int jb = t*64 + ss*32;
      // ---- d^2 tile via MFMA (AF direct from global; L1/L2-resident) ----
      const short8 afk = *(const short8*)&AFb[(size_t)(jb+lo5)*16 + hi*8];
      f32x16 zz = {};
      f32x16 d2 = __builtin_amdgcn_mfma_f32_32x32x16_bf16(afk, bfq, zz, 0,0,0);
      // ---- S^T = K Q^T from LDS (Q pre-scaled by 1/8) ----
      const short8 kf0 = *(const short8*)&kbc[ss*2048 + rb + (((0+hi)^rx)<<3)];
      const short8 kf1 = *(const short8*)&kbc[ss*2048 + rb + (((2+hi)^rx)<<3)];
      const short8 kf2 = *(const short8*)&kbc[ss*2048 + rb + (((4+hi)^rx)<<3)];
      const short8 kf3 = *(const short8*)&kbc[ss*2048 + rb + (((6+hi)^rx)<<3)];
      f32x16 st = {};
      st = __builtin_amdgcn_mfma_f32_32x32x16_bf16(kf0, qf[0], st, 0,0,0);
      st = __builtin_amdgcn_mfma_f32_32x32x16_bf16(kf1, qf[1], st, 0,0,0);
      st = __builtin_amdgcn_mfma_f32_32x32x16_bf16(kf2, qf[2], st, 0,0,0);
      st = __builtin_amdgcn_mfma_f32_32x32x16_bf16(kf3, qf[3], st, 0,0,0);
      // ---- p = exp(st - a*d), no max needed (logit range analysis) ----
      float p[16];
      #pragma unroll
      for (int r=0;r<16;r++){
        float d = __builtin_amdgcn_sqrtf(fmaxf(d2[r], 0.f));
        p[r] = __expf(fmaf(-ah, d, st[r]));
      }
      float s01=p[0]+p[1], s23=p[2]+p[3], s45=p[4]+p[5], s67=p[6]+p[7];
      float s89=p[8]+p[9], sab=p[10]+p[11], scd=p[12]+p[13], sef=p[14]+p[15];
      float rsum = ((s01+s23)+(s45+s67)) + ((s89+sab)+(scd+sef));
      rsum += __shfl_xor(rsum, 32);
      l_run += rsum;
      // ---- P -> bf16 A-fragments (cvt_pk + permlane32_swap), PV from LDS ----
      #pragma unroll
      for (int s=0;s<2;s++){
        uint w0, w1, w2, w3;
        asm("v_cvt_pk_bf16_f32 %0, %1, %2" : "=v"(w0) : "v"(p[8*s+0]), "v"(p[8*s+1]));
        asm("v_cvt_pk_bf16_f32 %0, %1, %2" : "=v"(w2) : "v"(p[8*s+4]), "v"(p[8*s+5]));
        asm("v_cvt_pk_bf16_f32 %0, %1, %2" : "=v"(w1) : "v"(p[8*s+2]), "v"(p[8*s+3]));
        asm("v_cvt_pk_bf16_f32 %0, %1, %2" : "=v"(w3) : "v"(p[8*s+6]), "v"(p[8*s+7]));
        asm volatile("v_permlane32_swap_b32 %0, %1" : "+v"(w0), "+v"(w2));
        asm volatile("v_permlane32_swap_b32 %0, %1" : "+v"(w1), "+v"(w3));
        uint4 aw; aw.x = w0; aw.y = w1; aw.z = w2; aw.w = w3;
        const short8 pa = __builtin_bit_cast(short8, aw);
        const int jcol = (ss<<2) + 2*s + hi;           // col16 within 64-wide tile
        const short8 v0 = *(const short8*)&vbc[       rb + ((jcol^rx)<<3)];
        const short8 v1 = *(const short8*)&vbc[2048 + rb + ((jcol^rx)<<3)];
        o0 = __builtin_amdgcn_mfma_f32_32x32x16_bf16(pa, v0, o0, 0,0,0);
        o1 = __builtin_amdgcn_mfma_f32_32x32x16_bf16(pa, v1, o1, 0,0,0);
      }
    }
  }
#undef STAGE

  // ---- normalize + store: O row q=q0+crow(r,hi), col d = dh*32 + lo5 ----
  #pragma unroll
  for (int r=0;r<16;r++){
    const int src = (r&3) + 8*(r>>2) + 4*hi;
    const float lr = __shfl(l_run, src);
    const float inv = 1.f/lr;
    const int i = q0 + src;
    O[((size_t)b*NSEQ + i)*DMODEL + h*DK + lo5]      = f2bf(o0[r]*inv);
    O[((size_t)b*NSEQ + i)*DMODEL + h*DK + 32 + lo5] = f2bf(o1[r]*inv);
  }
}

extern "C" void kernel_launch(void* const* d_in, const int* in_sizes, int n_in,
                              void* d_out, int out_size, void* d_ws, size_t ws_size,
                              hipStream_t stream) {
  const float* x   = (const float*)d_in[0];
  const float* pos = (const float*)d_in[1];
  const float* Wq  = (const float*)d_in[2];
  const float* bq  = (const float*)d_in[3];
  const float* Wk  = (const float*)d_in[4];
  const float* bk  = (const float*)d_in[5];
  const float* Wv  = (const float*)d_in[6];
  const float* bv  = (const float*)d_in[7];
  const float* Wo  = (const float*)d_in[8];
  const float* bo  = (const float*)d_in[9];
  const float* db  = (const float*)d_in[10];
  float* out = (float*)d_out;

  // workspace layout (48 MB, regions reused across phases):
  // 0-8MB   : xb (x bf16)            -> merged O (after attn)
  // 8-10MB  : Wqb                    -> AF(128K) + BF(128K)
  // 10-12MB : Wkb   (dead after qkv gemm)
  // 12-14MB : Wvb   (dead after qkv gemm)
  // 14-16MB : Wob   (live until k_gemm_out)
  // 16-24MB : Qb
  // 24-32MB : Kb
  // 32-40MB : Vtb
  char* ws = (char*)d_ws;
  ushort* xb   = (ushort*)(ws);
  ushort* Wqb  = (ushort*)(ws + ((size_t)8<<20));
  ushort* Wkb  = (ushort*)(ws + ((size_t)10<<20));
  ushort* Wvb  = (ushort*)(ws + ((size_t)12<<20));
  ushort* Wob  = (ushort*)(ws + ((size_t)14<<20));
  ushort* Qb   = (ushort*)(ws + ((size_t)16<<20));
  ushort* Kb   = (ushort*)(ws + ((size_t)24<<20));
  ushort* Vtb  = (ushort*)(ws + ((size_t)32<<20));
  ushort* AFt  = Wqb;                                  // reuse after qkv gemm
  ushort* BFt  = (ushort*)(ws + ((size_t)8<<20) + (128<<10));
  ushort* Omrg = xb;                                   // reuse after qkv gemm

  k_cvt<<<4096, 256, 0, stream>>>((const float4*)x,  (ushort4*)xb,  1048576);
  k_cvt<<<1024, 256, 0, stream>>>((const float4*)Wq, (ushort4*)Wqb, 262144);
  k_cvt<<<1024, 256, 0, stream>>>((const float4*)Wk, (ushort4*)Wkb, 262144);
  k_cvt<<<1024, 256, 0, stream>>>((const float4*)Wv, (ushort4*)Wvb, 262144);
  k_cvt<<<1024, 256, 0, stream>>>((const float4*)Wo, (ushort4*)Wob, 262144);
  k_gemm_qkv<<<768, 256, 0, stream>>>(xb, Wqb, Wkb, Wvb, bq, bk, bv, Qb, Kb, Vtb);
  k_geo<<<16, 256, 0, stream>>>(pos, AFt, BFt, 2*NSEQ);
  k_attn<<<dim3(16,NHEADS,2), 256, 0, stream>>>(Qb, Kb, Vtb, AFt, BFt, db, Omrg);
  k_gemm_out<<<256, 256, 0, stream>>>(Omrg, Wob, bo, out);
}